// Round 8
// baseline (138.954 us; speedup 1.0000x reference)
//
#include <hip/hip_runtime.h>
#include <hip/hip_bf16.h>

#define BIG 3.4e38f

constexpr int PLANE = 253 * 256;

// ---------- top-5 helpers ----------

// Merge two ascending sorted 5-lists, keep the 5 smallest in a[].
__device__ __forceinline__ void merge5(float a[5], const float* b) {
    float r[5];
#pragma unroll
    for (int k = 0; k < 5; ++k) {
        float best = BIG;
#pragma unroll
        for (int i = 0; i <= k + 1; ++i) {
            const int j = k + 1 - i;
            float va = (i == 0) ? -BIG : a[i - 1];
            float vb = (j == 0) ? -BIG : b[j - 1];
            best = fminf(best, fmaxf(va, vb));
        }
        r[k] = best;
    }
#pragma unroll
    for (int k = 0; k < 5; ++k) a[k] = r[k];
}

__device__ __forceinline__ void top5_insert(float m[5], float d) {
    if (d < m[4]) {
        m[4] = d;
#pragma unroll
        for (int k = 4; k > 0; --k) {
            float lo = fminf(m[k - 1], m[k]);
            float hi = fmaxf(m[k - 1], m[k]);
            m[k - 1] = lo;
            m[k] = hi;
        }
    }
}

// 5 smallest across wave, one value per lane (iterative min-extract;
// exact w.r.t. duplicates via ballot+ffs). Result sorted, in all lanes.
__device__ __forceinline__ void wave_top5_extract(float d, int lane,
                                                  float r[5]) {
#pragma unroll
    for (int k = 0; k < 5; ++k) {
        float v = d;
#pragma unroll
        for (int off = 32; off >= 1; off >>= 1)
            v = fminf(v, __shfl_xor(v, off, 64));
        r[k] = v;
        const unsigned long long ball = __ballot(d == v);
        const int src = (int)__ffsll(ball) - 1;
        if (lane == src) d = BIG;
    }
}

// 5 smallest of the union of per-lane ascending 5-lists (k-way merge by
// head-pop: global min of heads is the global min; pop exactly one).
__device__ __forceinline__ void wave_top5_pop(float m[5], int lane,
                                              float r[5]) {
#pragma unroll
    for (int k = 0; k < 5; ++k) {
        float v = m[0];
#pragma unroll
        for (int off = 32; off >= 1; off >>= 1)
            v = fminf(v, __shfl_xor(v, off, 64));
        r[k] = v;
        const unsigned long long ball = __ballot(m[0] == v);
        const int src = (int)__ffsll(ball) - 1;
        if (lane == src) {
            m[0] = m[1]; m[1] = m[2]; m[2] = m[3]; m[3] = m[4]; m[4] = BIG;
        }
    }
}

__device__ __forceinline__ void wave_merge_top5(float m[5]) {
#pragma unroll
    for (int off = 1; off < 64; off <<= 1) {
        float o[5];
#pragma unroll
        for (int k = 0; k < 5; ++k) o[k] = __shfl_xor(m[k], off, 64);
        merge5(m, o);
    }
}

__device__ __forceinline__ bool block_merge_top5(float m[5], float (*s_top)[5],
                                                 float r[5]) {
    const int wid = threadIdx.x >> 6;
    if ((threadIdx.x & 63) == 0) {
#pragma unroll
        for (int k = 0; k < 5; ++k) s_top[wid][k] = m[k];
    }
    __syncthreads();
    if (threadIdx.x == 0) {
#pragma unroll
        for (int k = 0; k < 5; ++k) r[k] = s_top[0][k];
        merge5(r, s_top[1]);
        merge5(r, s_top[2]);
        merge5(r, s_top[3]);
        return true;
    }
    return false;
}

// ---------- K1 v8: 16-way chunk split (4 channels/chunk) ---------------
// Round-7 counters: VGPR=24 allows 8 waves/SIMD but grid (1088 blocks =
// 4.25/CU) capped occupancy at ~37% -> VALUBusy 40%, dur 45-56 µs.
// Halving the chunk doubles the grid: 16 x 128 + 64 = 2112 blocks =
// 8.25 blocks/CU = ~33 waves/CU. Per-thread VALU halves; twice the
// resident waves hide the s_load/vmcnt waits. dist0 grows to 41.4 MB
// (cheap at HBM rates). tv still wave-uniform s_load straight from tgt0.
// Blocks [0,64): scale-1 (C=128, ps=1) full dist + block top-5 -> p2b.
__global__ __launch_bounds__(256) void dist_all_kernel(
    const float* __restrict__ src0, const float* __restrict__ tgt0,
    const int* __restrict__ pos0, const float* __restrict__ src1,
    const float* __restrict__ tgt1, const int* __restrict__ pos1,
    float* __restrict__ dist0, float* __restrict__ p2b) {
    __shared__ float stp[4][5][5];
    const int tid = threadIdx.x;
    const int lane = tid & 63;
    const int wv = tid >> 6;
    const int bx = blockIdx.x;

    if (bx >= 64) {
        // ---- scale 0: C=64, H=W=256, ps=3, chunk = 4 channels ----
        const int b = bx - 64;
        const int chunk = b >> 7;         // 0..15
        const int tile = b & 127;         // 64 quads x 2 halves
        const int h = (tile >> 1) * 4 + wv;
        const int hl = (h <= 252) ? h : 252;  // clamp loads in-bounds
        const int w0 = ((tile & 1) << 7) + 2 * lane;  // 0..254 even

        int th[10], tw[10];
#pragma unroll
        for (int t = 0; t < 10; ++t) {
            th[t] = __builtin_amdgcn_readfirstlane(pos0[2 * t]);
            tw[t] = __builtin_amdgcn_readfirstlane(pos0[2 * t + 1]);
        }

        float acc[10][2];
#pragma unroll
        for (int t = 0; t < 10; ++t) acc[t][0] = acc[t][1] = 0.f;

        const int c0 = chunk * 4;
        const float* sb = src0 + (size_t)c0 * 65536 + hl * 256 + w0;
        const float* tb = tgt0 + (size_t)c0 * 65536;
        for (int c = 0; c < 4; ++c) {
            const float* row = sb + (size_t)c * 65536;
            const float* tgc = tb + (size_t)c * 65536;
#pragma unroll
            for (int i = 0; i < 3; ++i) {
                const float4 a = *(const float4*)(row + i * 256);
#pragma unroll
                for (int t = 0; t < 10; ++t) {
                    const float* tg = tgc + (th[t] + i) * 256 + tw[t];
                    const float t0 = tg[0], t1 = tg[1], t2 = tg[2];  // s_load
                    acc[t][0] += fabsf(a.x - t0) + fabsf(a.y - t1) +
                                 fabsf(a.z - t2);
                    acc[t][1] += fabsf(a.y - t0) + fabsf(a.z - t1) +
                                 fabsf(a.w - t2);
                }
            }
        }

        if (h < 253) {
            float* dp = dist0 + (size_t)chunk * 10 * PLANE + h * 256 + w0;
#pragma unroll
            for (int t = 0; t < 10; ++t) {
                float2 o = {acc[t][0], acc[t][1]};
                *(float2*)(dp + (size_t)t * PLANE) = o;
            }
        }
    } else {
        // ---- scale 1: C=128, H=W=128, ps=1; 2 rows per block ----
        const int bb = bx;
        int th[5], tw[5];
#pragma unroll
        for (int t = 0; t < 5; ++t) {
            th[t] = __builtin_amdgcn_readfirstlane(pos1[2 * t]);
            tw[t] = __builtin_amdgcn_readfirstlane(pos1[2 * t + 1]);
        }
        const int w = tid & 127;
        const int h1 = bb * 2 + (tid >> 7);  // 0..127
        float acc[5] = {0.f, 0.f, 0.f, 0.f, 0.f};
        const float* sp = src1 + h1 * 128 + w;
        for (int c = 0; c < 128; ++c) {
            const float v = sp[(size_t)c * 16384];
#pragma unroll
            for (int t = 0; t < 5; ++t) {
                const float tv =
                    tgt1[(size_t)c * 16384 + th[t] * 128 + tw[t]];  // s_load
                acc[t] += fabsf(v - tv);
            }
        }
        const bool valid = (w < 127) && (h1 < 127);
#pragma unroll
        for (int t = 0; t < 5; ++t) {
            float r[5];
            wave_top5_extract(valid ? acc[t] : BIG, lane, r);
            if (lane == 0) {
#pragma unroll
                for (int k = 0; k < 5; ++k) stp[wv][t][k] = r[k];
            }
        }
        __syncthreads();
        if (tid < 5) {
            float r[5];
#pragma unroll
            for (int k = 0; k < 5; ++k) r[k] = stp[0][tid][k];
            merge5(r, stp[1][tid]);
            merge5(r, stp[2][tid]);
            merge5(r, stp[3][tid]);
            float* dst = p2b + (tid * 64 + bb) * 5;
#pragma unroll
            for (int k = 0; k < 5; ++k) dst[k] = r[k];
        }
    }
}

// ---------- K2: summed-plane top-5 (NO election, NO fences) ------------
// Round-6 lesson: last-block election's __threadfence() = device-scope
// L2 writeback/inv per wave x 640 blocks -> 71 µs at 1.35% VALUBusy.
// A separate 1-block K3 launch is ~2 µs. Never again.
// Grid (64, 10): 1 float4/thread summed over the 16 chunk planes.
__global__ __launch_bounds__(256) void top5_stage_kernel(
    const float* __restrict__ dist0, float* __restrict__ p2a) {
    __shared__ float s_top[4][5];
    const int tid = threadIdx.x;
    const int lane = tid & 63;
    const int t = blockIdx.y;
    const int f = blockIdx.x * 256 + tid;

    float m[5] = {BIG, BIG, BIG, BIG, BIG};
    if (f < PLANE / 4) {
        const float* base = dist0 + (size_t)t * PLANE + f * 4;
        float4 s = *(const float4*)base;
#pragma unroll
        for (int ch = 1; ch < 16; ++ch) {
            const float4 u = *(const float4*)(base + (size_t)ch * 10 * PLANE);
            s.x += u.x; s.y += u.y; s.z += u.z; s.w += u.w;
        }
        const int w0 = (f * 4) & 255;
        top5_insert(m, (w0 + 0 < 253) ? s.x : BIG);
        top5_insert(m, (w0 + 1 < 253) ? s.y : BIG);
        top5_insert(m, (w0 + 2 < 253) ? s.z : BIG);
        top5_insert(m, (w0 + 3 < 253) ? s.w : BIG);
    }
    float r[5];
    wave_top5_pop(m, lane, r);
    float rr[5];
    if (block_merge_top5(r, s_top, rr)) {
        float* dst = p2a + (t * 64 + blockIdx.x) * 5;
#pragma unroll
        for (int k = 0; k < 5; ++k) dst[k] = rr[k];
    }
}

// ---------- K3: parallel-over-targets final merge + scalar write --------
// Output word: high16 = f32 bits, low16 = RNE bf16 bits (dtype-proof).
__global__ __launch_bounds__(256) void final_merge_kernel(
    const float* __restrict__ p2a, int na,
    const float* __restrict__ p2b, int nb,
    unsigned int* __restrict__ out) {
    __shared__ float s_sum[15];
    const int lane = threadIdx.x & 63;
    const int wv = threadIdx.x >> 6;
#pragma unroll
    for (int rt = 0; rt < 4; ++rt) {
        const int t = wv * 4 + rt;
        if (t < 15) {
            const float* base = (t < 10) ? p2a + t * na : p2b + (t - 10) * nb;
            const int n = (t < 10) ? na : nb;
            const float scale =
                (t < 10) ? 1.f / (576.f * 5.f) : 1.f / (128.f * 5.f);
            float m[5] = {BIG, BIG, BIG, BIG, BIG};
            for (int b0 = 0; b0 < n; b0 += 64)
                if (b0 + lane < n) top5_insert(m, base[b0 + lane]);
            wave_merge_top5(m);
            if (lane == 0)
                s_sum[t] = (m[0] + m[1] + m[2] + m[3] + m[4]) * scale;
        }
    }
    __syncthreads();
    if (threadIdx.x == 0) {
        float total = 0.f;
#pragma unroll
        for (int t = 0; t < 15; ++t) total += s_sum[t];
        union { float f; unsigned int i; } uf;
        uf.f = total * 0.1f;
        unsigned int bf = (uf.i + 0x7FFFu + ((uf.i >> 16) & 1u)) >> 16;
        out[0] = (uf.i & 0xFFFF0000u) | (bf & 0xFFFFu);
    }
}

// ---------- fallback path (proven, tiny ws) ----------
template <int C, int H, int PS, int WM>
__global__ __launch_bounds__(256) void dist_top5_kernel(
    const float* __restrict__ src, const float* __restrict__ tgt,
    const int* __restrict__ pos, float* __restrict__ part) {
    constexpr int W = H;
    constexpr int K = C * PS * PS;
    constexpr int P = WM * WM;
    __shared__ float tlv[K];
    __shared__ float s_top[4][5];
    const int t = blockIdx.y;
    const int th = pos[2 * t], tw = pos[2 * t + 1];
    for (int idx = threadIdx.x; idx < K; idx += 256) {
        int c = idx / (PS * PS);
        int rem = idx - c * PS * PS;
        int i = rem / PS, j = rem - i * PS;
        tlv[idx] = tgt[(c * H + th + i) * W + tw + j];
    }
    __syncthreads();
    const int p = blockIdx.x * 256 + threadIdx.x;
    float d = BIG;
    if (p < P) {
        const int h = p / WM, w = p - h * WM;
        float acc = 0.f;
        for (int c = 0; c < C; ++c)
#pragma unroll
            for (int i = 0; i < PS; ++i) {
                const float* r = src + (c * H + h + i) * W + w;
                const float* tr = &tlv[(c * PS + i) * PS];
#pragma unroll
                for (int j = 0; j < PS; ++j) acc += fabsf(r[j] - tr[j]);
            }
        d = acc;
    }
    float m[5] = {d, BIG, BIG, BIG, BIG};
    wave_merge_top5(m);
    float r[5];
    if (block_merge_top5(m, s_top, r)) {
        float* dst = part + (t * gridDim.x + blockIdx.x) * 5;
#pragma unroll
        for (int k = 0; k < 5; ++k) dst[k] = r[k];
    }
}

extern "C" void kernel_launch(void* const* d_in, const int* in_sizes, int n_in,
                              void* d_out, int out_size, void* d_ws, size_t ws_size,
                              hipStream_t stream) {
    const float* src0 = (const float*)d_in[0];  // [1,64,256,256] f32
    const float* tgt0 = (const float*)d_in[1];
    const float* src1 = (const float*)d_in[2];  // [1,128,128,128] f32
    const float* tgt1 = (const float*)d_in[3];
    const int* pos0 = (const int*)d_in[4];      // [10,2]
    const int* pos1 = (const int*)d_in[5];      // [5,2]
    unsigned int* out = (unsigned int*)d_out;

    constexpr size_t NDIST = (size_t)16 * 10 * PLANE;  // 10.36M floats
    constexpr size_t NP2A = 10 * 64 * 5;               // 3200
    constexpr size_t NP2B = 5 * 64 * 5;                // 1600
    const size_t need = (NDIST + NP2A + NP2B) * 4;     // ~41.5 MB

    if (ws_size >= need) {
        float* dist0 = (float*)d_ws;
        float* p2a = dist0 + NDIST;
        float* p2b = p2a + NP2A;

        // K1: scale-1 (64 blocks) + scale-0 chunk partials (2048 blocks).
        dist_all_kernel<<<dim3(2112), 256, 0, stream>>>(
            src0, tgt0, pos0, src1, tgt1, pos1, dist0, p2b);
        // K2: summed-plane top-5 per (target, 64-block slice).
        top5_stage_kernel<<<dim3(64, 10), 256, 0, stream>>>(dist0, p2a);
        // K3: final merge (10 x 320 values + 5 x 320 values).
        final_merge_kernel<<<dim3(1), 256, 0, stream>>>(p2a, 320, p2b, 320,
                                                        out);
    } else {
        // Fallback: proven path (~57KB of ws).
        float* part0 = (float*)d_ws;
        float* part1 = part0 + 10 * 251 * 5;
        dist_top5_kernel<64, 256, 3, 253>
            <<<dim3(251, 10), 256, 0, stream>>>(src0, tgt0, pos0, part0);
        dist_top5_kernel<128, 128, 1, 127>
            <<<dim3(64, 5), 256, 0, stream>>>(src1, tgt1, pos1, part1);
        final_merge_kernel<<<dim3(1), 256, 0, stream>>>(part0, 1255, part1, 320, out);
    }
}

// Round 9
// 135.010 us; speedup vs baseline: 1.0292x; 1.0292x over previous
//
#include <hip/hip_runtime.h>
#include <hip/hip_bf16.h>

#define BIG 3.4e38f

constexpr int PLANE = 253 * 256;

// ---------- top-5 helpers ----------

// Merge two ascending sorted 5-lists, keep the 5 smallest in a[].
__device__ __forceinline__ void merge5(float a[5], const float* b) {
    float r[5];
#pragma unroll
    for (int k = 0; k < 5; ++k) {
        float best = BIG;
#pragma unroll
        for (int i = 0; i <= k + 1; ++i) {
            const int j = k + 1 - i;
            float va = (i == 0) ? -BIG : a[i - 1];
            float vb = (j == 0) ? -BIG : b[j - 1];
            best = fminf(best, fmaxf(va, vb));
        }
        r[k] = best;
    }
#pragma unroll
    for (int k = 0; k < 5; ++k) a[k] = r[k];
}

__device__ __forceinline__ void top5_insert(float m[5], float d) {
    if (d < m[4]) {
        m[4] = d;
#pragma unroll
        for (int k = 4; k > 0; --k) {
            float lo = fminf(m[k - 1], m[k]);
            float hi = fmaxf(m[k - 1], m[k]);
            m[k - 1] = lo;
            m[k] = hi;
        }
    }
}

// 5 smallest of the union of per-lane ascending 5-lists (k-way merge by
// head-pop: global min of heads is the global min; pop exactly one).
__device__ __forceinline__ void wave_top5_pop(float m[5], int lane,
                                              float r[5]) {
#pragma unroll
    for (int k = 0; k < 5; ++k) {
        float v = m[0];
#pragma unroll
        for (int off = 32; off >= 1; off >>= 1)
            v = fminf(v, __shfl_xor(v, off, 64));
        r[k] = v;
        const unsigned long long ball = __ballot(m[0] == v);
        const int src = (int)__ffsll(ball) - 1;
        if (lane == src) {
            m[0] = m[1]; m[1] = m[2]; m[2] = m[3]; m[3] = m[4]; m[4] = BIG;
        }
    }
}

__device__ __forceinline__ void wave_merge_top5(float m[5]) {
#pragma unroll
    for (int off = 1; off < 64; off <<= 1) {
        float o[5];
#pragma unroll
        for (int k = 0; k < 5; ++k) o[k] = __shfl_xor(m[k], off, 64);
        merge5(m, o);
    }
}

__device__ __forceinline__ bool block_merge_top5(float m[5], float (*s_top)[5],
                                                 float r[5]) {
    const int wid = threadIdx.x >> 6;
    if ((threadIdx.x & 63) == 0) {
#pragma unroll
        for (int k = 0; k < 5; ++k) s_top[wid][k] = m[k];
    }
    __syncthreads();
    if (threadIdx.x == 0) {
#pragma unroll
        for (int k = 0; k < 5; ++k) r[k] = s_top[0][k];
        merge5(r, s_top[1]);
        merge5(r, s_top[2]);
        merge5(r, s_top[3]);
        return true;
    }
    return false;
}

// ---------- K1: round-0's proven kernel (fastest measured K1) ----------
// Why this structure wins (rounds 2-8 all lost to it):
//  * tv reads are WAVE-UNIFORM LDS broadcasts (all 64 lanes read the
//    same tl float4 -> single conflict-free broadcast instruction);
//  * 4 positions/thread -> ~48 VALU per tv fetch (amortization);
//  * LDS-pipe and VALU loads per CU are balanced (~11 µs each) and
//    overlap across waves.
// s_load tv (r7/r8) stalled at VGPR=24 w/ zero ILP: plateau 47 µs.
// One fix vs round 0: load-row clamp 250 -> 252 (250 corrupted rows
// 251-252 with row-250 data; 252 is exact for all written rows h<253).
// Grid (64, 9). y<8: scale-0 chunk y (8 channels), block = 4 rows x
// 256 cols, partial sums -> dist0 (w-padded planes, float4 stores).
// y==8: scale-1 (C=128, ps=1) full dist + block top-5 -> p2b.
__global__ __launch_bounds__(256) void dist_all_kernel(
    const float* __restrict__ src0, const float* __restrict__ tgt0,
    const int* __restrict__ pos0, const float* __restrict__ src1,
    const float* __restrict__ tgt1, const int* __restrict__ pos1,
    float* __restrict__ dist0, float* __restrict__ p2b) {
    __shared__ float tl[960];      // scale0: 10*8*12 padded; scale1: 640
    __shared__ float s_top[4][5];

    if (blockIdx.y < 8) {
        // ---- scale 0: C=64, H=W=256, ps=3, CCH=8 ----
        constexpr int H = 256, W = 256, HW = H * W, T = 10, CCH = 8;
        const int c0 = blockIdx.y * CCH;

        for (int idx = threadIdx.x; idx < T * CCH * 9; idx += 256) {
            int t = idx / (CCH * 9);
            int rem = idx - t * (CCH * 9);
            int cc = rem / 9;
            int r2 = rem - cc * 9;
            int i = r2 / 3, j = r2 - i * 3;
            int th = pos0[2 * t], tw = pos0[2 * t + 1];
            tl[((t * CCH + cc) * 3 + i) * 4 + j] =
                tgt0[(size_t)(c0 + cc) * HW + (th + i) * W + (tw + j)];
        }
        __syncthreads();

        const int tx = threadIdx.x & 63;
        const int ty = threadIdx.x >> 6;
        const int h = blockIdx.x * 4 + ty;          // valid < 253
        const int hl = (h <= 252) ? h : 252;        // exact clamp (fix)
        const int w0 = tx * 4;                      // 0..252
        const int bw = (w0 <= 248) ? w0 + 4 : 248;  // clamped 2nd col

        float acc[T][4];
#pragma unroll
        for (int t = 0; t < T; ++t)
#pragma unroll
            for (int n = 0; n < 4; ++n) acc[t][n] = 0.f;

        const float* sb = src0 + (size_t)c0 * HW + hl * W;
        for (int cc = 0; cc < CCH; ++cc) {
            const float* row0 = sb + (size_t)cc * HW;
#pragma unroll
            for (int i = 0; i < 3; ++i) {
                const float4 a = *(const float4*)(row0 + i * W + w0);
                const float2 b = *(const float2*)(row0 + i * W + bw);
                const float r[6] = {a.x, a.y, a.z, a.w, b.x, b.y};
#pragma unroll
                for (int t = 0; t < T; ++t) {
                    const float4 tv =
                        *(const float4*)&tl[((t * CCH + cc) * 3 + i) * 4];
#pragma unroll
                    for (int n = 0; n < 4; ++n)
                        acc[t][n] += fabsf(r[n] - tv.x) +
                                     fabsf(r[n + 1] - tv.y) +
                                     fabsf(r[n + 2] - tv.z);
                }
            }
        }

        if (h < 253) {
            float* dp = dist0 + (size_t)blockIdx.y * T * PLANE + h * 256 + w0;
#pragma unroll
            for (int t = 0; t < T; ++t) {
                float4 o = {acc[t][0], acc[t][1], acc[t][2], acc[t][3]};
                *(float4*)(dp + (size_t)t * PLANE) = o;
            }
        }
    } else {
        // ---- scale 1: C=128, H=W=128, ps=1 — full dist + block top-5 ----
        constexpr int H = 128, W = 128, HW = H * W, T = 5, C = 128;
        for (int idx = threadIdx.x; idx < T * C; idx += 256) {
            int t = idx / C, cc = idx - t * C;
            tl[idx] =
                tgt1[(size_t)cc * HW + pos1[2 * t] * W + pos1[2 * t + 1]];
        }
        __syncthreads();

        const int w = threadIdx.x & 127;
        const int h = blockIdx.x * 2 + (threadIdx.x >> 7);  // 0..127
        float acc[T] = {0.f, 0.f, 0.f, 0.f, 0.f};
        const float* sp = src1 + h * W + w;
        for (int cc = 0; cc < C; ++cc) {
            const float v = sp[(size_t)cc * HW];
#pragma unroll
            for (int t = 0; t < T; ++t) acc[t] += fabsf(v - tl[t * C + cc]);
        }
        const bool valid = (h < 127) && (w < 127);
#pragma unroll
        for (int t = 0; t < T; ++t) {
            float m[5] = {valid ? acc[t] : BIG, BIG, BIG, BIG, BIG};
            wave_merge_top5(m);
            float r[5];
            if (block_merge_top5(m, s_top, r)) {
                float* dst = p2b + (t * 64 + blockIdx.x) * 5;
#pragma unroll
                for (int k = 0; k < 5; ++k) dst[k] = r[k];
            }
            __syncthreads();  // s_top reuse across targets
        }
    }
}

// ---------- K2: summed-plane top-5 (round-7 proven; no fences) ---------
// 64 blocks/target (vs round-0's 16 which was latency-bound): 1 float4
// per thread summed over the 8 chunk planes, pop-merge epilogue.
__global__ __launch_bounds__(256) void top5_stage_kernel(
    const float* __restrict__ dist0, float* __restrict__ p2a) {
    __shared__ float s_top[4][5];
    const int tid = threadIdx.x;
    const int lane = tid & 63;
    const int t = blockIdx.y;
    const int f = blockIdx.x * 256 + tid;

    float m[5] = {BIG, BIG, BIG, BIG, BIG};
    if (f < PLANE / 4) {
        const float* base = dist0 + (size_t)t * PLANE + f * 4;
        float4 s = *(const float4*)base;
#pragma unroll
        for (int ch = 1; ch < 8; ++ch) {
            const float4 u = *(const float4*)(base + (size_t)ch * 10 * PLANE);
            s.x += u.x; s.y += u.y; s.z += u.z; s.w += u.w;
        }
        const int w0 = (f * 4) & 255;
        top5_insert(m, (w0 + 0 < 253) ? s.x : BIG);
        top5_insert(m, (w0 + 1 < 253) ? s.y : BIG);
        top5_insert(m, (w0 + 2 < 253) ? s.z : BIG);
        top5_insert(m, (w0 + 3 < 253) ? s.w : BIG);
    }
    float r[5];
    wave_top5_pop(m, lane, r);
    float rr[5];
    if (block_merge_top5(r, s_top, rr)) {
        float* dst = p2a + (t * 64 + blockIdx.x) * 5;
#pragma unroll
        for (int k = 0; k < 5; ++k) dst[k] = rr[k];
    }
}

// ---------- K3: parallel-over-targets final merge + scalar write --------
// Output word: high16 = f32 bits, low16 = RNE bf16 bits (dtype-proof).
__global__ __launch_bounds__(256) void final_merge_kernel(
    const float* __restrict__ p2a, int na,
    const float* __restrict__ p2b, int nb,
    unsigned int* __restrict__ out) {
    __shared__ float s_sum[15];
    const int lane = threadIdx.x & 63;
    const int wv = threadIdx.x >> 6;
#pragma unroll
    for (int rt = 0; rt < 4; ++rt) {
        const int t = wv * 4 + rt;
        if (t < 15) {
            const float* base = (t < 10) ? p2a + t * na : p2b + (t - 10) * nb;
            const int n = (t < 10) ? na : nb;
            const float scale =
                (t < 10) ? 1.f / (576.f * 5.f) : 1.f / (128.f * 5.f);
            float m[5] = {BIG, BIG, BIG, BIG, BIG};
            for (int b0 = 0; b0 < n; b0 += 64)
                if (b0 + lane < n) top5_insert(m, base[b0 + lane]);
            wave_merge_top5(m);
            if (lane == 0)
                s_sum[t] = (m[0] + m[1] + m[2] + m[3] + m[4]) * scale;
        }
    }
    __syncthreads();
    if (threadIdx.x == 0) {
        float total = 0.f;
#pragma unroll
        for (int t = 0; t < 15; ++t) total += s_sum[t];
        union { float f; unsigned int i; } uf;
        uf.f = total * 0.1f;
        unsigned int bf = (uf.i + 0x7FFFu + ((uf.i >> 16) & 1u)) >> 16;
        out[0] = (uf.i & 0xFFFF0000u) | (bf & 0xFFFFu);
    }
}

// ---------- fallback path (proven, tiny ws) ----------
template <int C, int H, int PS, int WM>
__global__ __launch_bounds__(256) void dist_top5_kernel(
    const float* __restrict__ src, const float* __restrict__ tgt,
    const int* __restrict__ pos, float* __restrict__ part) {
    constexpr int W = H;
    constexpr int K = C * PS * PS;
    constexpr int P = WM * WM;
    __shared__ float tlv[K];
    __shared__ float s_top[4][5];
    const int t = blockIdx.y;
    const int th = pos[2 * t], tw = pos[2 * t + 1];
    for (int idx = threadIdx.x; idx < K; idx += 256) {
        int c = idx / (PS * PS);
        int rem = idx - c * PS * PS;
        int i = rem / PS, j = rem - i * PS;
        tlv[idx] = tgt[(c * H + th + i) * W + tw + j];
    }
    __syncthreads();
    const int p = blockIdx.x * 256 + threadIdx.x;
    float d = BIG;
    if (p < P) {
        const int h = p / WM, w = p - h * WM;
        float acc = 0.f;
        for (int c = 0; c < C; ++c)
#pragma unroll
            for (int i = 0; i < PS; ++i) {
                const float* r = src + (c * H + h + i) * W + w;
                const float* tr = &tlv[(c * PS + i) * PS];
#pragma unroll
                for (int j = 0; j < PS; ++j) acc += fabsf(r[j] - tr[j]);
            }
        d = acc;
    }
    float m[5] = {d, BIG, BIG, BIG, BIG};
    wave_merge_top5(m);
    float r[5];
    if (block_merge_top5(m, s_top, r)) {
        float* dst = part + (t * gridDim.x + blockIdx.x) * 5;
#pragma unroll
        for (int k = 0; k < 5; ++k) dst[k] = r[k];
    }
}

extern "C" void kernel_launch(void* const* d_in, const int* in_sizes, int n_in,
                              void* d_out, int out_size, void* d_ws, size_t ws_size,
                              hipStream_t stream) {
    const float* src0 = (const float*)d_in[0];  // [1,64,256,256] f32
    const float* tgt0 = (const float*)d_in[1];
    const float* src1 = (const float*)d_in[2];  // [1,128,128,128] f32
    const float* tgt1 = (const float*)d_in[3];
    const int* pos0 = (const int*)d_in[4];      // [10,2]
    const int* pos1 = (const int*)d_in[5];      // [5,2]
    unsigned int* out = (unsigned int*)d_out;

    constexpr size_t NDIST = (size_t)8 * 10 * PLANE;  // 5.18M floats
    constexpr size_t NP2A = 10 * 64 * 5;              // 3200
    constexpr size_t NP2B = 5 * 64 * 5;               // 1600
    const size_t need = (NDIST + NP2A + NP2B) * 4;    // ~20.75 MB

    if (ws_size >= need) {
        float* dist0 = (float*)d_ws;
        float* p2a = dist0 + NDIST;
        float* p2b = p2a + NP2A;

        // K1: scale-0 chunk partials (512 blocks) + scale-1 (64 blocks).
        dist_all_kernel<<<dim3(64, 9), 256, 0, stream>>>(
            src0, tgt0, pos0, src1, tgt1, pos1, dist0, p2b);
        // K2: summed-plane top-5 per (target, 64-block slice).
        top5_stage_kernel<<<dim3(64, 10), 256, 0, stream>>>(dist0, p2a);
        // K3: final merge (10 x 320 values + 5 x 320 values).
        final_merge_kernel<<<dim3(1), 256, 0, stream>>>(p2a, 320, p2b, 320,
                                                        out);
    } else {
        // Fallback: proven path (~57KB of ws).
        float* part0 = (float*)d_ws;
        float* part1 = part0 + 10 * 251 * 5;
        dist_top5_kernel<64, 256, 3, 253>
            <<<dim3(251, 10), 256, 0, stream>>>(src0, tgt0, pos0, part0);
        dist_top5_kernel<128, 128, 1, 127>
            <<<dim3(64, 5), 256, 0, stream>>>(src1, tgt1, pos1, part1);
        final_merge_kernel<<<dim3(1), 256, 0, stream>>>(part0, 1255, part1, 320, out);
    }
}